// Round 4
// baseline (454.542 us; speedup 1.0000x reference)
//
#include <hip/hip_runtime.h>
#include <hip/hip_bf16.h>
#include <stdint.h>

#define B_    64
#define S_    2048
#define ENC_  512
#define ATTN_ 256

typedef __bf16 bf16;
typedef bf16  bf16x8 __attribute__((ext_vector_type(8)));
typedef float f32x4  __attribute__((ext_vector_type(4)));

__device__ __forceinline__ float fexp2(float x) {
#if __has_builtin(__builtin_amdgcn_exp2f)
    return __builtin_amdgcn_exp2f(x);
#else
    return exp2f(x);
#endif
}
__device__ __forceinline__ float frcp(float x) {
#if __has_builtin(__builtin_amdgcn_rcpf)
    return __builtin_amdgcn_rcpf(x);
#else
    return 1.0f / x;
#endif
}
// tanh(x) = 1 - 2/(e^{2x}+1); overflow-safe (exp2->inf => 1, ->0 => -1)
__device__ __forceinline__ float fast_tanh(float x) {
    float e = fexp2(x * 2.8853900817779268f);
    return 1.0f - 2.0f * frcp(e + 1.0f);
}

__device__ __forceinline__ void async_copy16(const void* g, void* l) {
#if __has_builtin(__builtin_amdgcn_global_load_lds)
    __builtin_amdgcn_global_load_lds(
        (__attribute__((address_space(1))) void*)(g),
        (__attribute__((address_space(3))) void*)(l), 16, 0, 0);
#else
    *(uint4*)l = *(const uint4*)g;
#endif
}

__device__ __forceinline__ bf16x8 cvt8(float4 a, float4 b) {
    bf16x8 r;
    r[0]=(bf16)a.x; r[1]=(bf16)a.y; r[2]=(bf16)a.z; r[3]=(bf16)a.w;
    r[4]=(bf16)b.x; r[5]=(bf16)b.y; r[6]=(bf16)b.z; r[7]=(bf16)b.w;
    return r;
}

// ---------------- setup: WT transpose->bf16 (blocks 0..511) + dec_proj (512..575)
// dec_proj blocks also zero ctx_acc/esum (atomicAdd targets in k_scores_ctx).
__global__ __launch_bounds__(256) void k_setup(const float* __restrict__ W_enc,
                                               const float* __restrict__ dec_state,
                                               const float* __restrict__ W_dec,
                                               bf16* __restrict__ WT,
                                               float* __restrict__ dp,
                                               float* __restrict__ ctx_acc,
                                               float* __restrict__ esum) {
    int blk = blockIdx.x;
    if (blk < 512) {
        int idx = blk * 256 + threadIdx.x;      // 0..131071
        int n = idx >> 9;                        // /512
        int k = idx & 511;
        WT[idx] = (bf16)W_enc[k * ATTN_ + n];    // coalesced writes
    } else {
        int b = blk - 512;
        int a = threadIdx.x;
        *(float2*)(ctx_acc + b * 512 + a * 2) = make_float2(0.f, 0.f);
        if (a == 0) esum[b] = 0.f;
        const float* ds = dec_state + b * 512;
        float acc = 0.f;
#pragma unroll 8
        for (int d = 0; d < 512; ++d)
            acc += ds[d] * W_dec[d * ATTN_ + a];
        dp[b * ATTN_ + a] = acc;
    }
}

// ---------------- scores + fused context, barrier-decoupled ---------------
// A: global->register direct (NO LDS, NO barrier dependence), depth-2 prefetch.
// B: WT (L2-resident) staged per K-chunk of 128 into 64KB LDS; 2 barriers per
// chunk, 8 total. Inside a chunk: 4 K-steps with zero synchronization.
// Wave w owns rows [w*32, w*32+32) x all 256 cols.
__global__ __launch_bounds__(256, 2) void k_scores_ctx(
    const float* __restrict__ enc,    // [131072][512]
    const bf16*  __restrict__ WT,     // [256][512] (n-major, k contiguous)
    const float* __restrict__ dp,     // [64][256]
    const float* __restrict__ v,      // [256]
    float* __restrict__ attn_e,       // [64][2048] unnormalized e
    float* __restrict__ ctx_acc,      // [64][512] fp32 accumulator
    float* __restrict__ esum)         // [64]
{
    __shared__ __align__(16) bf16 Bs[32768];     // 64 KB: [col=256][Kc=128] swizzled
    __shared__ float ew[128];
    __shared__ f32x4 vred[128];

    const int tid  = threadIdx.x;
    const int wave = tid >> 6;
    const int lane = tid & 63;
    const int l15  = lane & 15;
    const int q    = lane >> 4;
    const int m0   = blockIdx.x * 128;
    const int b    = blockIdx.x >> 4;            // 16 blocks per batch
    const int slab = blockIdx.x & 15;

    // staging constants: thread t stages storage-chunklet (t&15) of cols i*16+(t>>4)
    const int c0  = tid >> 4;
    const int chk = (tid & 15) ^ ((tid >> 4) & 7);   // logical chunklet (constant)

    // A addresses: lane -> row = m0 + wave*32 + mt*16 + l15, k-offset q*8
    const float* base0 = enc + (size_t)(m0 + wave * 32 + l15) * 512 + q * 8;
    const float* base1 = base0 + (size_t)16 * 512;

    f32x4 acc0[16], acc1[16];
    const f32x4 zero4 = {0.f, 0.f, 0.f, 0.f};
#pragma unroll
    for (int nt = 0; nt < 16; ++nt) { acc0[nt] = zero4; acc1[nt] = zero4; }

    // ---- prologue: issue A(0)->X, A(1)->Y ----
    float4 X0, X1, X2, X3, Y0, Y1, Y2, Y3;
    X0 = *(const float4*)(base0);        X1 = *(const float4*)(base0 + 4);
    X2 = *(const float4*)(base1);        X3 = *(const float4*)(base1 + 4);
    Y0 = *(const float4*)(base0 + 32);   Y1 = *(const float4*)(base0 + 36);
    Y2 = *(const float4*)(base1 + 32);   Y3 = *(const float4*)(base1 + 36);

#define STEP(s, A0, A1, A2, A3)                                               \
    do {                                                                      \
        bf16x8 af0 = cvt8(A0, A1);                                            \
        bf16x8 af1 = cvt8(A2, A3);                                            \
        if ((s) + 2 < 16) {                                                   \
            const float* p0 = base0 + ((s) + 2) * 32;                         \
            const float* p1 = base1 + ((s) + 2) * 32;                         \
            A0 = *(const float4*)(p0); A1 = *(const float4*)(p0 + 4);         \
            A2 = *(const float4*)(p1); A3 = *(const float4*)(p1 + 4);         \
        }                                                                     \
        const int jq4 = ((s) & 3) * 4 + q;                                    \
        _Pragma("unroll")                                                     \
        for (int nt = 0; nt < 16; ++nt) {                                     \
            int col = nt * 16 + l15;                                          \
            int p   = jq4 ^ (col & 7);                                        \
            bf16x8 bfv = *(const bf16x8*)(Bs + col * 128 + p * 8);            \
            acc0[nt] = __builtin_amdgcn_mfma_f32_16x16x32_bf16(af0, bfv, acc0[nt], 0, 0, 0); \
            acc1[nt] = __builtin_amdgcn_mfma_f32_16x16x32_bf16(af1, bfv, acc1[nt], 0, 0, 0); \
        }                                                                     \
    } while (0)

#pragma unroll
    for (int ci = 0; ci < 4; ++ci) {
        __syncthreads();                         // prior chunk reads retired
        // stage chunk ci: 64 KB from WT (L2-hot); linear LDS dest,
        // swizzle applied on the global source (storage chunklet = logical^(col&7))
#pragma unroll
        for (int i = 0; i < 16; ++i) {
            async_copy16(WT + (size_t)(i * 16 + c0) * 512 + ci * 128 + chk * 8,
                         Bs + (i * 256 + tid) * 8);
        }
        __syncthreads();                         // staged (compiler drains vmcnt)

        STEP(ci * 4 + 0, X0, X1, X2, X3);
        STEP(ci * 4 + 1, Y0, Y1, Y2, Y3);
        STEP(ci * 4 + 2, X0, X1, X2, X3);
        STEP(ci * 4 + 3, Y0, Y1, Y2, Y3);
    }
#undef STEP

    // ---- epilogue: per-wave complete rows; no cross-wave reduction --------
    float dpv[16], vv[16];
#pragma unroll
    for (int nt = 0; nt < 16; ++nt) {
        int col = nt * 16 + l15;
        dpv[nt] = dp[b * 256 + col];
        vv[nt]  = v[col];
    }

    float es_local = 0.f;
#pragma unroll
    for (int mt = 0; mt < 2; ++mt) {
#pragma unroll
        for (int r = 0; r < 4; ++r) {
            float s = 0.f;
#pragma unroll
            for (int nt = 0; nt < 16; ++nt) {
                float c = (mt == 0) ? acc0[nt][r] : acc1[nt][r];
                s += fast_tanh(c + dpv[nt]) * vv[nt];
            }
            s += __shfl_xor(s, 1, 16);
            s += __shfl_xor(s, 2, 16);
            s += __shfl_xor(s, 4, 16);
            s += __shfl_xor(s, 8, 16);
            if (l15 == 0) {
                int row = wave * 32 + mt * 16 + q * 4 + r;
                float e = fexp2(s * 1.4426950408889634f);  // |s| <~ 11: fp32-safe
                ew[row] = e;
                attn_e[(size_t)b * 2048 + slab * 128 + row] = e;
                es_local += e;
            }
        }
    }
    // reduce e-sum across the 4 leader lanes (l15==0) of this wave
    es_local += __shfl_xor(es_local, 16);
    es_local += __shfl_xor(es_local, 32);
    if (lane == 0) atomicAdd(esum + b, es_local);
    __syncthreads();

    // ---- fused context GEMV over this block's 128 rows (L2/L3-hot) --------
    {
        const float* eb = enc + (size_t)m0 * 512;
        const int col = tid * 2;
        float cx = 0.f, cy = 0.f;
#pragma unroll
        for (int g = 0; g < 16; ++g) {
            float2 ev[8];
            float  wv[8];
#pragma unroll
            for (int j = 0; j < 8; ++j) {
                ev[j] = *(const float2*)(eb + (size_t)(g * 8 + j) * 512 + col);
                wv[j] = ew[g * 8 + j];
            }
#pragma unroll
            for (int j = 0; j < 8; ++j) { cx += ev[j].x * wv[j]; cy += ev[j].y * wv[j]; }
        }
        float* cp = ctx_acc + (size_t)b * 512 + col;
        atomicAdd(cp + 0, cx);
        atomicAdd(cp + 1, cy);
    }
}

// ---------------- finalize: divide attn row and ctx by esum ---------------
__global__ __launch_bounds__(256) void k_finalize(const float* __restrict__ ctx_acc,
                                                  const float* __restrict__ esum,
                                                  float* __restrict__ ctx,
                                                  float* __restrict__ attn) {
    const int b   = blockIdx.x;
    const int tid = threadIdx.x;
    const float inv = 1.0f / esum[b];

    float4* ap = (float4*)(attn + (size_t)b * 2048);
#pragma unroll
    for (int i = 0; i < 2; ++i) {
        float4 t = ap[tid + 256 * i];
        t.x *= inv; t.y *= inv; t.z *= inv; t.w *= inv;
        ap[tid + 256 * i] = t;
    }
    float2 c = *(const float2*)(ctx_acc + (size_t)b * 512 + tid * 2);
    *(float2*)(ctx + (size_t)b * 512 + tid * 2) = make_float2(c.x * inv, c.y * inv);
}

extern "C" void kernel_launch(void* const* d_in, const int* in_sizes, int n_in,
                              void* d_out, int out_size, void* d_ws, size_t ws_size,
                              hipStream_t stream) {
    const float* enc       = (const float*)d_in[0];
    const float* dec_state = (const float*)d_in[1];
    const float* W_enc     = (const float*)d_in[2];
    const float* W_dec     = (const float*)d_in[3];
    const float* v         = (const float*)d_in[4];

    float* ctx  = (float*)d_out;                 // [64,512]
    float* attn = (float*)d_out + 64 * 512;      // [64,2048] weights (e -> normalized in place)

    // workspace: WT bf16 256KB | dp fp32 64KB | ctx_acc fp32 128KB | esum 256B
    char*  ws      = (char*)d_ws;
    bf16*  WT      = (bf16*)ws;
    float* dp      = (float*)(ws + 256 * 1024);
    float* ctx_acc = (float*)(ws + 256 * 1024 + 64 * 1024);
    float* esum    = (float*)(ws + 256 * 1024 + 64 * 1024 + 128 * 1024);

    k_setup      <<<576,  256, 0, stream>>>(W_enc, dec_state, W_dec, WT, dp, ctx_acc, esum);
    k_scores_ctx <<<1024, 256, 0, stream>>>(enc, WT, dp, v, attn, ctx_acc, esum);
    k_finalize   <<<64,   256, 0, stream>>>(ctx_acc, esum, ctx, attn);
}

// Round 5
// 451.516 us; speedup vs baseline: 1.0067x; 1.0067x over previous
//
#include <hip/hip_runtime.h>
#include <hip/hip_bf16.h>
#include <stdint.h>

#define B_    64
#define S_    2048
#define ENC_  512
#define ATTN_ 256

typedef __bf16 bf16;
typedef bf16  bf16x8 __attribute__((ext_vector_type(8)));
typedef float f32x4  __attribute__((ext_vector_type(4)));

__device__ __forceinline__ float fexp2(float x) {
#if __has_builtin(__builtin_amdgcn_exp2f)
    return __builtin_amdgcn_exp2f(x);
#else
    return exp2f(x);
#endif
}
__device__ __forceinline__ float frcp(float x) {
#if __has_builtin(__builtin_amdgcn_rcpf)
    return __builtin_amdgcn_rcpf(x);
#else
    return 1.0f / x;
#endif
}
// tanh(x) = 1 - 2/(e^{2x}+1); overflow-safe (exp2->inf => 1, ->0 => -1)
__device__ __forceinline__ float fast_tanh(float x) {
    float e = fexp2(x * 2.8853900817779268f);
    return 1.0f - 2.0f * frcp(e + 1.0f);
}

__device__ __forceinline__ void async_copy16(const void* g, void* l) {
#if __has_builtin(__builtin_amdgcn_global_load_lds)
    __builtin_amdgcn_global_load_lds(
        (__attribute__((address_space(1))) void*)(g),
        (__attribute__((address_space(3))) void*)(l), 16, 0, 0);
#else
    *(uint4*)l = *(const uint4*)g;
#endif
}

__device__ __forceinline__ bf16x8 cvt8(float4 a, float4 b) {
    bf16x8 r;
    r[0]=(bf16)a.x; r[1]=(bf16)a.y; r[2]=(bf16)a.z; r[3]=(bf16)a.w;
    r[4]=(bf16)b.x; r[5]=(bf16)b.y; r[6]=(bf16)b.z; r[7]=(bf16)b.w;
    return r;
}

// ---------------- setup: WT transpose->bf16 (blocks 0..511) + dec_proj (512..575)
// dec_proj blocks also zero ctx_acc/esum (atomicAdd targets in k_scores_ctx).
__global__ __launch_bounds__(256) void k_setup(const float* __restrict__ W_enc,
                                               const float* __restrict__ dec_state,
                                               const float* __restrict__ W_dec,
                                               bf16* __restrict__ WT,
                                               float* __restrict__ dp,
                                               float* __restrict__ ctx_acc,
                                               float* __restrict__ esum) {
    int blk = blockIdx.x;
    if (blk < 512) {
        int idx = blk * 256 + threadIdx.x;      // 0..131071
        int n = idx >> 9;                        // /512
        int k = idx & 511;
        WT[idx] = (bf16)W_enc[k * ATTN_ + n];    // coalesced writes
    } else {
        int b = blk - 512;
        int a = threadIdx.x;
        *(float2*)(ctx_acc + b * 512 + a * 2) = make_float2(0.f, 0.f);
        if (a == 0) esum[b] = 0.f;
        const float* ds = dec_state + b * 512;
        float acc = 0.f;
#pragma unroll 8
        for (int d = 0; d < 512; ++d)
            acc += ds[d] * W_dec[d * ATTN_ + a];
        dp[b * ATTN_ + a] = acc;
    }
}

// ---------------- scores + fused context, ROLLED chunk loop ---------------
// v5: identical tiling/swizzle/prefetch to v4, but the chunk loop is a real
// loop (#pragma unroll 1): body = stage(16 copies) + 4 K-steps ~= 3.6 KB of
// code, I$-resident. v4's fully-unrolled ~14KB loop thrashed the shared
// 32KB/2CU instruction cache -> all-pipes-idle signature.
__global__ __launch_bounds__(256, 2) void k_scores_ctx(
    const float* __restrict__ enc,    // [131072][512]
    const bf16*  __restrict__ WT,     // [256][512] (n-major, k contiguous)
    const float* __restrict__ dp,     // [64][256]
    const float* __restrict__ v,      // [256]
    float* __restrict__ attn_e,       // [64][2048] unnormalized e
    float* __restrict__ ctx_acc,      // [64][512] fp32 accumulator
    float* __restrict__ esum)         // [64]
{
    __shared__ __align__(16) bf16 Bs[32768];     // 64 KB: [col=256][Kc=128] swizzled
    __shared__ float ew[128];

    const int tid  = threadIdx.x;
    const int wave = tid >> 6;
    const int lane = tid & 63;
    const int l15  = lane & 15;
    const int q    = lane >> 4;
    const int m0   = blockIdx.x * 128;
    const int b    = blockIdx.x >> 4;            // 16 blocks per batch
    const int slab = blockIdx.x & 15;

    // staging constants: thread t stages storage-chunklet (t&15) of cols i*16+(t>>4)
    const int c0  = tid >> 4;
    const int chk = (tid & 15) ^ ((tid >> 4) & 7);   // logical chunklet (constant)

    // A addresses: lane -> row = m0 + wave*32 + mt*16 + l15, k-offset q*8
    const float* base0 = enc + (size_t)(m0 + wave * 32 + l15) * 512 + q * 8;
    const float* base1 = base0 + (size_t)16 * 512;

    f32x4 acc0[16], acc1[16];
    const f32x4 zero4 = {0.f, 0.f, 0.f, 0.f};
#pragma unroll
    for (int nt = 0; nt < 16; ++nt) { acc0[nt] = zero4; acc1[nt] = zero4; }

    // ---- prologue: issue A(0)->X, A(1)->Y ----
    float4 X0, X1, X2, X3, Y0, Y1, Y2, Y3;
    X0 = *(const float4*)(base0);        X1 = *(const float4*)(base0 + 4);
    X2 = *(const float4*)(base1);        X3 = *(const float4*)(base1 + 4);
    Y0 = *(const float4*)(base0 + 32);   Y1 = *(const float4*)(base0 + 36);
    Y2 = *(const float4*)(base1 + 32);   Y3 = *(const float4*)(base1 + 36);

    // STEP j (compile-time j in 0..3): consume one A reg-buffer, prefetch the
    // same buffer for step ks+2 (ks = ci*4+j), 32 MFMAs against LDS chunk.
#define STEP(j, PF, A0, A1, A2, A3)                                           \
    do {                                                                      \
        bf16x8 af0 = cvt8(A0, A1);                                            \
        bf16x8 af1 = cvt8(A2, A3);                                            \
        if (PF) {                                                             \
            const float* p0 = abase0 + (j + 2) * 32;                          \
            const float* p1 = abase1 + (j + 2) * 32;                          \
            A0 = *(const float4*)(p0); A1 = *(const float4*)(p0 + 4);         \
            A2 = *(const float4*)(p1); A3 = *(const float4*)(p1 + 4);         \
        }                                                                     \
        const int jq4 = (j) * 4 + q;                                          \
        _Pragma("unroll")                                                     \
        for (int nt = 0; nt < 16; ++nt) {                                     \
            int col = nt * 16 + l15;                                          \
            int p   = jq4 ^ (col & 7);                                        \
            bf16x8 bfv = *(const bf16x8*)(Bs + col * 128 + p * 8);            \
            acc0[nt] = __builtin_amdgcn_mfma_f32_16x16x32_bf16(af0, bfv, acc0[nt], 0, 0, 0); \
            acc1[nt] = __builtin_amdgcn_mfma_f32_16x16x32_bf16(af1, bfv, acc1[nt], 0, 0, 0); \
        }                                                                     \
    } while (0)

    const float* abase0 = base0;
    const float* abase1 = base1;
    const bf16*  wbase  = WT + (size_t)c0 * 512 + chk * 8;

#pragma unroll 1
    for (int ci = 0; ci < 4; ++ci) {
        const bool pf23 = (ci != 3);
        __syncthreads();                         // prior chunk reads retired
        // stage chunk ci: 64 KB from WT (L2-hot); linear LDS dest,
        // swizzle applied on the global source (storage chunklet = logical^(col&7))
#pragma unroll
        for (int i = 0; i < 16; ++i) {
            async_copy16(wbase + (size_t)i * (16 * 512),
                         Bs + (i * 256 + tid) * 8);
        }
        __syncthreads();                         // staged (compiler drains vmcnt)

        STEP(0, true, X0, X1, X2, X3);
        STEP(1, true, Y0, Y1, Y2, Y3);
        STEP(2, pf23, X0, X1, X2, X3);
        STEP(3, pf23, Y0, Y1, Y2, Y3);

        abase0 += 128;
        abase1 += 128;
        wbase  += 128;
    }
#undef STEP

    // ---- epilogue: per-wave complete rows; no cross-wave reduction --------
    float dpv[16], vv[16];
#pragma unroll
    for (int nt = 0; nt < 16; ++nt) {
        int col = nt * 16 + l15;
        dpv[nt] = dp[b * 256 + col];
        vv[nt]  = v[col];
    }

    float es_local = 0.f;
#pragma unroll
    for (int mt = 0; mt < 2; ++mt) {
#pragma unroll
        for (int r = 0; r < 4; ++r) {
            float s = 0.f;
#pragma unroll
            for (int nt = 0; nt < 16; ++nt) {
                float c = (mt == 0) ? acc0[nt][r] : acc1[nt][r];
                s += fast_tanh(c + dpv[nt]) * vv[nt];
            }
            s += __shfl_xor(s, 1, 16);
            s += __shfl_xor(s, 2, 16);
            s += __shfl_xor(s, 4, 16);
            s += __shfl_xor(s, 8, 16);
            if (l15 == 0) {
                int row = wave * 32 + mt * 16 + q * 4 + r;
                float e = fexp2(s * 1.4426950408889634f);  // |s| <~ 11: fp32-safe
                ew[row] = e;
                attn_e[(size_t)b * 2048 + slab * 128 + row] = e;
                es_local += e;
            }
        }
    }
    // reduce e-sum across the 4 leader lanes (l15==0) of this wave
    es_local += __shfl_xor(es_local, 16);
    es_local += __shfl_xor(es_local, 32);
    if (lane == 0) atomicAdd(esum + b, es_local);
    __syncthreads();

    // ---- fused context GEMV over this block's 128 rows (L2/L3-hot) --------
    {
        const float* eb = enc + (size_t)m0 * 512;
        const int col = tid * 2;
        float cx = 0.f, cy = 0.f;
#pragma unroll 4
        for (int g = 0; g < 16; ++g) {
            float2 ev[8];
            float  wv[8];
#pragma unroll
            for (int j = 0; j < 8; ++j) {
                ev[j] = *(const float2*)(eb + (size_t)(g * 8 + j) * 512 + col);
                wv[j] = ew[g * 8 + j];
            }
#pragma unroll
            for (int j = 0; j < 8; ++j) { cx += ev[j].x * wv[j]; cy += ev[j].y * wv[j]; }
        }
        float* cp = ctx_acc + (size_t)b * 512 + col;
        atomicAdd(cp + 0, cx);
        atomicAdd(cp + 1, cy);
    }
}

// ---------------- finalize: divide attn row and ctx by esum ---------------
__global__ __launch_bounds__(256) void k_finalize(const float* __restrict__ ctx_acc,
                                                  const float* __restrict__ esum,
                                                  float* __restrict__ ctx,
                                                  float* __restrict__ attn) {
    const int b   = blockIdx.x;
    const int tid = threadIdx.x;
    const float inv = 1.0f / esum[b];

    float4* ap = (float4*)(attn + (size_t)b * 2048);
#pragma unroll
    for (int i = 0; i < 2; ++i) {
        float4 t = ap[tid + 256 * i];
        t.x *= inv; t.y *= inv; t.z *= inv; t.w *= inv;
        ap[tid + 256 * i] = t;
    }
    float2 c = *(const float2*)(ctx_acc + (size_t)b * 512 + tid * 2);
    *(float2*)(ctx + (size_t)b * 512 + tid * 2) = make_float2(c.x * inv, c.y * inv);
}

extern "C" void kernel_launch(void* const* d_in, const int* in_sizes, int n_in,
                              void* d_out, int out_size, void* d_ws, size_t ws_size,
                              hipStream_t stream) {
    const float* enc       = (const float*)d_in[0];
    const float* dec_state = (const float*)d_in[1];
    const float* W_enc     = (const float*)d_in[2];
    const float* W_dec     = (const float*)d_in[3];
    const float* v         = (const float*)d_in[4];

    float* ctx  = (float*)d_out;                 // [64,512]
    float* attn = (float*)d_out + 64 * 512;      // [64,2048] weights (e -> normalized in place)

    // workspace: WT bf16 256KB | dp fp32 64KB | ctx_acc fp32 128KB | esum 256B
    char*  ws      = (char*)d_ws;
    bf16*  WT      = (bf16*)ws;
    float* dp      = (float*)(ws + 256 * 1024);
    float* ctx_acc = (float*)(ws + 256 * 1024 + 64 * 1024);
    float* esum    = (float*)(ws + 256 * 1024 + 64 * 1024 + 128 * 1024);

    k_setup      <<<576,  256, 0, stream>>>(W_enc, dec_state, W_dec, WT, dp, ctx_acc, esum);
    k_scores_ctx <<<1024, 256, 0, stream>>>(enc, WT, dp, v, attn, ctx_acc, esum);
    k_finalize   <<<64,   256, 0, stream>>>(ctx_acc, esum, ctx, attn);
}